// Round 13
// baseline (432.215 us; speedup 1.0000x reference)
//
#include <hip/hip_runtime.h>

typedef unsigned short u16;
typedef __bf16 bf16x8 __attribute__((ext_vector_type(8)));
typedef float f32x4 __attribute__((ext_vector_type(4)));

__device__ __forceinline__ u16 f2bf(float f) {
    unsigned int u = __float_as_uint(f);
    unsigned int r = (u + 0x7FFFu + ((u >> 16) & 1u)) >> 16;
    return (u16)r;
}
__device__ __forceinline__ float bf_lo(unsigned int u) { return __uint_as_float(u << 16); }
__device__ __forceinline__ float bf_hi(unsigned int u) { return __uint_as_float(u & 0xFFFF0000u); }

#define GLOAD_LDS(gp, lp) \
    __builtin_amdgcn_global_load_lds( \
        (const __attribute__((address_space(1))) unsigned int*)(gp), \
        (__attribute__((address_space(3))) unsigned int*)(lp), 16, 0, 0)

// ---------------- graph preprocessing ----------------

__global__ void hist_k(const int* __restrict__ dst, int* __restrict__ deg, int nE) {
    int e = blockIdx.x * 256 + threadIdx.x;
    if (e < nE) atomicAdd(&deg[dst[e]], 1);
}

__global__ void scan_block_k(const int* __restrict__ deg, int* __restrict__ scanned,
                             int* __restrict__ bsums, int n) {
    __shared__ int s[1024];
    int i = blockIdx.x * 1024 + threadIdx.x;
    int v = (i < n) ? deg[i] : 0;
    s[threadIdx.x] = v;
    __syncthreads();
    for (int off = 1; off < 1024; off <<= 1) {
        int t = (threadIdx.x >= off) ? s[threadIdx.x - off] : 0;
        __syncthreads();
        s[threadIdx.x] += t;
        __syncthreads();
    }
    if (i < n) scanned[i] = s[threadIdx.x];
    if (threadIdx.x == 1023) bsums[blockIdx.x] = s[1023];
}

// inline bsums prefix (nb<=49), + dinv + wptr
__global__ void scan_final_dinv_k(const int* __restrict__ scanned, const int* __restrict__ deg,
                                  const int* __restrict__ bsums, int* __restrict__ rowptr,
                                  int* __restrict__ wptr, float* __restrict__ dinv,
                                  int n, int nE) {
    int i = blockIdx.x * 256 + threadIdx.x;
    if (i < n) {
        int pre = 0;
        int nbi = i >> 10;
        for (int j = 0; j < nbi; ++j) pre += bsums[j];
        int rp = scanned[i] - deg[i] + pre;
        rowptr[i] = rp;
        wptr[i] = rp;
        dinv[i] = rsqrtf((float)deg[i] + 1.0f);
    }
    if (i == 0) rowptr[n] = nE;
}

__global__ void csr_fill_k(const int* __restrict__ src, const int* __restrict__ dst,
                           int* __restrict__ wptr, const float* __restrict__ dinv,
                           int* __restrict__ eidx, float* __restrict__ ecoef, int nE) {
    int e = blockIdx.x * 256 + threadIdx.x;
    if (e >= nE) return;
    int d = dst[e], s = src[e];
    int p = atomicAdd(&wptr[d], 1);
    eidx[p] = s;
    ecoef[p] = dinv[s] * dinv[d];
}

// ---------------- single prep kernel: Wp chain, cvec, fc1^T, fc2xlabel ----------------
// blocks 0..511: Wp row chain; 512: c1/c2; 513..576: Bfc1; 577..704: Wc/bc

__global__ __launch_bounds__(256) void prep_all_k(
    const float* __restrict__ W1, const float* __restrict__ W2, const float* __restrict__ W3,
    const float* __restrict__ b1, const float* __restrict__ b2,
    const float* __restrict__ fc1_w, const float* __restrict__ fc2_w,
    const float* __restrict__ fc2_b, const float* __restrict__ labelm,
    u16* __restrict__ Wp, float* __restrict__ c1, float* __restrict__ c2,
    u16* __restrict__ Bfc1, u16* __restrict__ Wc, float* __restrict__ bc) {
    __shared__ float lds[16706];   // 66,824B: fc2 role needs 128*129+128+2
    const int b = blockIdx.x, tid = threadIdx.x;
    if (b < 512) {
        float* row = lds;          // 256
        float* t1r = lds + 256;    // 192
        row[tid] = (tid < 256) ? W1[b * 256 + tid] : 0.f;
        __syncthreads();
        if (tid < 192) {
            float s = 0.f;
            for (int k = 0; k < 256; ++k) s = fmaf(row[k], W2[k * 192 + tid], s);
            t1r[tid] = s;
        }
        __syncthreads();
        if (tid < 128) {
            float s = 0.f;
            for (int m = 0; m < 192; ++m) s = fmaf(t1r[m], W3[m * 128 + tid], s);
            Wp[(size_t)tid * 512 + b] = f2bf(s);
        }
    } else if (b == 512) {
        float* t1b = lds;
        if (tid < 192) {
            float s = 0.f;
            for (int k = 0; k < 256; ++k) s = fmaf(b1[k], W2[k * 192 + tid], s);
            t1b[tid] = s;
        }
        __syncthreads();
        if (tid < 128) {
            float a = 0.f, bb = 0.f;
            for (int m = 0; m < 192; ++m) {
                a  = fmaf(t1b[m], W3[m * 128 + tid], a);
                bb = fmaf(b2[m],  W3[m * 128 + tid], bb);
            }
            c1[tid] = a; c2[tid] = bb;
        }
    } else if (b < 577) {
        int idx = (b - 513) * 256 + tid;
        if (idx < 128 * 128) {
            int nn = idx >> 7, k = idx & 127;
            Bfc1[idx] = f2bf(fc1_w[k * 128 + nn]);
        }
    } else {
        const int cb = b - 577;    // 0..127
        float* w  = lds;            // 128*129
        float* lm = lds + 16512;    // 128
        float* red = lds + 16640;   // 2
        for (int t = tid; t < 128 * 128; t += 256)
            w[(t >> 7) * 129 + (t & 127)] = fc2_w[t];
        __syncthreads();
        for (int cc = 0; cc < 8; ++cc) {
            int c = cb * 8 + cc;
            if (tid < 128) lm[tid] = (c < 1000) ? labelm[(size_t)c * 128 + tid] : 0.f;
            __syncthreads();
            if (tid < 128) {
                float sum = 0.f;
                const float* wr = &w[tid * 129];
                for (int j = 0; j < 128; ++j) sum = fmaf(wr[j], lm[j], sum);
                Wc[(size_t)c * 128 + tid] = f2bf(sum);
                float p = fc2_b[tid] * lm[tid];
                for (int off = 32; off > 0; off >>= 1) p += __shfl_down(p, off);
                if ((tid & 63) == 0) red[tid >> 6] = p;
            }
            __syncthreads();
            if (tid == 0) bc[c] = red[0] + red[1];
            __syncthreads();
        }
    }
}

// ---------------- bf16 MFMA GEMM (BM=BN=128, BK=64, 4 waves, XCD swizzle) ----------------
// NTSTORE: use nontemporal stores for the f32 output (write-once stream)

template <bool CASTA, bool OUTF32, bool BIAS, bool RELU>
__global__ __launch_bounds__(256) void gemm_mfma(
    const void* __restrict__ Ap, const u16* __restrict__ Bt,
    const float* __restrict__ bias, void* __restrict__ Cout,
    int K, int Nout, int ldc, int Mout, int lgny, int Arows) {
    __shared__ __align__(16) u16 As[128 * 64];
    __shared__ __align__(16) u16 Bs[128 * 64];
    const int tid  = threadIdx.x;
    const int lane = tid & 63;
    const int w    = tid >> 6;
    const int wm   = w >> 1, wn = w & 1;

    const int nwg = gridDim.x, orig = blockIdx.x;
    const int q = nwg >> 3, r = nwg & 7;
    const int xcd = orig & 7, off = orig >> 3;
    const int tile = (xcd < r ? xcd * (q + 1) : r * (q + 1) + (xcd - r) * q) + off;
    const int ny = 1 << lgny;
    const int tx = tile >> lgny, ty = tile & (ny - 1);
    const size_t bm = (size_t)tx * 128;
    const size_t bn = (size_t)ty * 128;

    const int l7 = lane & 7;
    const int l3 = lane >> 3;
    const int kcs = l7 ^ l3;

    f32x4 acc[4][4] = {};

    for (int k0 = 0; k0 < K; k0 += 64) {
        if constexpr (CASTA) {
            const float* Af = (const float*)Ap;
            const int row = tid >> 1;
            const int half = tid & 1;
            const size_t grow = bm + row;
            const bool valid = grow < (size_t)Arows;
            const float4* g4 = (const float4*)(Af + grow * K + k0 + half * 32);
            float4 f[8];
#pragma unroll
            for (int j = 0; j < 8; ++j)
                f[j] = valid ? g4[j] : make_float4(0.f, 0.f, 0.f, 0.f);
#pragma unroll
            for (int j = 0; j < 4; ++j) {
                int kc = (half * 4 + j) ^ (row & 7);
                uint4 o;
                o.x = (unsigned)f2bf(f[2 * j].x)     | ((unsigned)f2bf(f[2 * j].y) << 16);
                o.y = (unsigned)f2bf(f[2 * j].z)     | ((unsigned)f2bf(f[2 * j].w) << 16);
                o.z = (unsigned)f2bf(f[2 * j + 1].x) | ((unsigned)f2bf(f[2 * j + 1].y) << 16);
                o.w = (unsigned)f2bf(f[2 * j + 1].z) | ((unsigned)f2bf(f[2 * j + 1].w) << 16);
                *(uint4*)((char*)As + row * 128 + kc * 16) = o;
            }
#pragma unroll
            for (int it = 0; it < 4; ++it) {
                const int r0 = w * 32 + it * 8;
                const u16* gB = Bt + ((size_t)(bn + r0 + l3) * K + k0) + kcs * 8;
                GLOAD_LDS(gB, Bs + r0 * 64);
            }
        } else {
            const u16* A = (const u16*)Ap;
#pragma unroll
            for (int it = 0; it < 4; ++it) {
                const int r0 = w * 32 + it * 8;
                const u16* gA = A + ((size_t)(bm + r0 + l3) * K + k0) + kcs * 8;
                GLOAD_LDS(gA, As + r0 * 64);
                const u16* gB = Bt + ((size_t)(bn + r0 + l3) * K + k0) + kcs * 8;
                GLOAD_LDS(gB, Bs + r0 * 64);
            }
        }
        __syncthreads();

#pragma unroll
        for (int ks = 0; ks < 2; ++ks) {
            bf16x8 av[4], bv[4];
#pragma unroll
            for (int i = 0; i < 4; ++i) {
                int row = wm * 64 + i * 16 + (lane & 15);
                int kc = (ks * 4 + (lane >> 4)) ^ (lane & 7);
                av[i] = *(const bf16x8*)((const char*)As + row * 128 + kc * 16);
            }
#pragma unroll
            for (int j = 0; j < 4; ++j) {
                int nn = wn * 64 + j * 16 + (lane & 15);
                int kc = (ks * 4 + (lane >> 4)) ^ (lane & 7);
                bv[j] = *(const bf16x8*)((const char*)Bs + nn * 128 + kc * 16);
            }
#pragma unroll
            for (int i = 0; i < 4; ++i)
#pragma unroll
                for (int j = 0; j < 4; ++j)
                    acc[i][j] = __builtin_amdgcn_mfma_f32_16x16x32_bf16(av[i], bv[j], acc[i][j], 0, 0, 0);
        }
        __syncthreads();
    }

    const int ccol  = lane & 15;
    const int crow4 = (lane >> 4) * 4;
#pragma unroll
    for (int i = 0; i < 4; ++i) {
#pragma unroll
        for (int j = 0; j < 4; ++j) {
#pragma unroll
            for (int r2 = 0; r2 < 4; ++r2) {
                size_t gr = bm + wm * 64 + i * 16 + crow4 + r2;
                size_t gc = bn + wn * 64 + j * 16 + ccol;
                if (gr < (size_t)Mout && gc < (size_t)Nout) {
                    float v = acc[i][j][r2];
                    if constexpr (BIAS) v += bias[gc];
                    if constexpr (RELU) v = fmaxf(v, 0.f);
                    if constexpr (OUTF32)
                        __builtin_nontemporal_store(v, &((float*)Cout)[gr * ldc + gc]);
                    else
                        ((u16*)Cout)[gr * ldc + gc] = f2bf(v);
                }
            }
        }
    }
}

// ---------------- aggregation: 16-lane subgroups, 16 nodes/block, 8x unroll ----------------
// MODE 0: also write u1[node]; MODE 1: plain; MODE 2: inline u2 + rank-1 corrections

template <int MODE>
__global__ __launch_bounds__(256) void agg128_k(
    const u16* __restrict__ xw, const int* __restrict__ rowptr,
    const int* __restrict__ eidx, const float* __restrict__ ecoef,
    const float* __restrict__ dinv, u16* __restrict__ out,
    float* __restrict__ u1, const float* __restrict__ c1,
    const float* __restrict__ c2, const float* __restrict__ b3, int n) {
    const int tid = threadIdx.x;
    const int sub = tid >> 4;
    const int fl  = tid & 15;
    int node = blockIdx.x * 16 + sub;
    if (node >= n) return;

    const uint4* xv = (const uint4*)xw;
    float di = dinv[node];
    float s = di * di;
    uint4 a = xv[(size_t)node * 16 + fl];
    float acc[8];
    acc[0] = s * bf_lo(a.x); acc[1] = s * bf_hi(a.x);
    acc[2] = s * bf_lo(a.y); acc[3] = s * bf_hi(a.y);
    acc[4] = s * bf_lo(a.z); acc[5] = s * bf_hi(a.z);
    acc[6] = s * bf_lo(a.w); acc[7] = s * bf_hi(a.w);
    float usum = 0.f;

    const int beg = rowptr[node], end = rowptr[node + 1];
    int e = beg;
    for (; e + 7 < end; e += 8) {
        int sn[8]; float cf[8]; uint4 v[8];
#pragma unroll
        for (int q = 0; q < 8; ++q) { sn[q] = eidx[e + q]; cf[q] = ecoef[e + q]; }
#pragma unroll
        for (int q = 0; q < 8; ++q) v[q] = xv[(size_t)sn[q] * 16 + fl];
#pragma unroll
        for (int q = 0; q < 8; ++q) {
            if constexpr (MODE == 0) usum += cf[q];
            if constexpr (MODE == 2) usum = fmaf(cf[q], u1[sn[q]], usum);
            acc[0] = fmaf(cf[q], bf_lo(v[q].x), acc[0]); acc[1] = fmaf(cf[q], bf_hi(v[q].x), acc[1]);
            acc[2] = fmaf(cf[q], bf_lo(v[q].y), acc[2]); acc[3] = fmaf(cf[q], bf_hi(v[q].y), acc[3]);
            acc[4] = fmaf(cf[q], bf_lo(v[q].z), acc[4]); acc[5] = fmaf(cf[q], bf_hi(v[q].z), acc[5]);
            acc[6] = fmaf(cf[q], bf_lo(v[q].w), acc[6]); acc[7] = fmaf(cf[q], bf_hi(v[q].w), acc[7]);
        }
    }
    for (; e < end; ++e) {
        int sn = eidx[e];
        float c = ecoef[e];
        uint4 v = xv[(size_t)sn * 16 + fl];
        if constexpr (MODE == 0) usum += c;
        if constexpr (MODE == 2) usum = fmaf(c, u1[sn], usum);
        acc[0] = fmaf(c, bf_lo(v.x), acc[0]); acc[1] = fmaf(c, bf_hi(v.x), acc[1]);
        acc[2] = fmaf(c, bf_lo(v.y), acc[2]); acc[3] = fmaf(c, bf_hi(v.y), acc[3]);
        acc[4] = fmaf(c, bf_lo(v.z), acc[4]); acc[5] = fmaf(c, bf_hi(v.z), acc[5]);
        acc[6] = fmaf(c, bf_lo(v.w), acc[6]); acc[7] = fmaf(c, bf_hi(v.w), acc[7]);
    }

    if constexpr (MODE == 0) {
        if (fl == 0) u1[node] = s + usum;
    }
    if constexpr (MODE == 2) {
        float u1n = u1[node];
        float u2n = s * u1n + usum;
        float4 c1a = ((const float4*)c1)[fl * 2], c1b = ((const float4*)c1)[fl * 2 + 1];
        float4 c2a = ((const float4*)c2)[fl * 2], c2b = ((const float4*)c2)[fl * 2 + 1];
        float4 b3a = ((const float4*)b3)[fl * 2], b3b = ((const float4*)b3)[fl * 2 + 1];
        acc[0] += u2n * c1a.x + u1n * c2a.x + b3a.x;
        acc[1] += u2n * c1a.y + u1n * c2a.y + b3a.y;
        acc[2] += u2n * c1a.z + u1n * c2a.z + b3a.z;
        acc[3] += u2n * c1a.w + u1n * c2a.w + b3a.w;
        acc[4] += u2n * c1b.x + u1n * c2b.x + b3b.x;
        acc[5] += u2n * c1b.y + u1n * c2b.y + b3b.y;
        acc[6] += u2n * c1b.z + u1n * c2b.z + b3b.z;
        acc[7] += u2n * c1b.w + u1n * c2b.w + b3b.w;
    }

    uint4 o;
    o.x = (unsigned)f2bf(acc[0]) | ((unsigned)f2bf(acc[1]) << 16);
    o.y = (unsigned)f2bf(acc[2]) | ((unsigned)f2bf(acc[3]) << 16);
    o.z = (unsigned)f2bf(acc[4]) | ((unsigned)f2bf(acc[5]) << 16);
    o.w = (unsigned)f2bf(acc[6]) | ((unsigned)f2bf(acc[7]) << 16);
    ((uint4*)out)[(size_t)node * 16 + fl] = o;
}

// ---------------- launcher ----------------

extern "C" void kernel_launch(void* const* d_in, const int* in_sizes, int n_in,
                              void* d_out, int out_size, void* d_ws, size_t ws_size,
                              hipStream_t stream) {
    const float* nodes  = (const float*)d_in[0];
    const int*   edges  = (const int*)d_in[1];
    const float* labelm = (const float*)d_in[2];
    const float* W1 = (const float*)d_in[3];
    const float* b1 = (const float*)d_in[4];
    const float* W2 = (const float*)d_in[5];
    const float* b2 = (const float*)d_in[6];
    const float* W3 = (const float*)d_in[7];
    const float* b3 = (const float*)d_in[8];
    const float* fc1_w = (const float*)d_in[9];
    const float* fc1_b = (const float*)d_in[10];
    const float* fc2_w = (const float*)d_in[11];
    const float* fc2_b = (const float*)d_in[12];
    float* out = (float*)d_out;

    const int DIM = 512, N3 = 128, NC = 1000;
    const int n  = in_sizes[0] / DIM;   // 50000
    const int nE = in_sizes[1] / 2;     // 800000
    const int Mpad = 50048;             // 391 * 128
    const int* src = edges;
    const int* dst = edges + nE;

    // d_out scratch: Y, Z (dead before preds writes)
    u16* Y = (u16*)((char*)d_out + 67108864);      // 12.8MB
    u16* Z = (u16*)((char*)d_out + 100663296);     // 12.8MB

    // ws layout (bytes)
    char* ws = (char*)d_ws;
    u16*   Q      = (u16*)(ws);                  // 12,812,288
    u16*   Rb     = (u16*)(ws + 12812288);       // 12,812,288
    u16*   Wp     = (u16*)(ws + 26017792);       // 131,072
    u16*   Bfc1   = (u16*)(ws + 26148864);       // 32,768
    u16*   Wc     = (u16*)(ws + 26181632);       // 262,144
    float* bc     = (float*)(ws + 26443776);     // 4,096
    float* c1     = (float*)(ws + 26447872);     // 512
    float* c2     = (float*)(ws + 26448384);     // 512
    float* u1     = (float*)(ws + 26448896);     // 200,000
    int*   deg_i  = (int*)(ws + 26848896);       // 200,000
    float* dinv   = (float*)(ws + 27048896);     // 200,000
    int*   rowptr = (int*)(ws + 27248896);       // 200,064
    int*   wptr   = (int*)(ws + 27448960);       // 200,000
    int*   scanned= (int*)(ws + 27648960);       // 200,000
    int*   bsums  = (int*)(ws + 27848960);       // 256
    int*   eidx   = (int*)(ws + 27849216);       // 3,200,000
    float* ecoef  = (float*)(ws + 31049216);     // 3,200,000 (end ~34.2MB)

    // graph preprocessing (5 dispatches incl. memset)
    hipMemsetAsync(deg_i, 0, (size_t)n * 4, stream);
    hist_k<<<(nE + 255) / 256, 256, 0, stream>>>(dst, deg_i, nE);
    int nb = (n + 1023) / 1024;
    scan_block_k<<<nb, 1024, 0, stream>>>(deg_i, scanned, bsums, n);
    scan_final_dinv_k<<<(n + 255) / 256, 256, 0, stream>>>(scanned, deg_i, bsums, rowptr, wptr, dinv, n, nE);
    csr_fill_k<<<(nE + 255) / 256, 256, 0, stream>>>(src, dst, wptr, dinv, eidx, ecoef, nE);

    // all weight prep in one kernel
    prep_all_k<<<705, 256, 0, stream>>>(W1, W2, W3, b1, b2, fc1_w, fc2_w, fc2_b, labelm,
                                        Wp, c1, c2, Bfc1, Wc, bc);

    const int gx = Mpad / 128;  // 391
    dim3 blk(256);
    const int gagg = (n + 15) / 16;   // 3125 blocks

    // Y = cast(nodes) @ Wp^T
    gemm_mfma<true, false, false, false><<<gx, blk, 0, stream>>>(nodes, Wp, nullptr, Y, 512, N3, N3, Mpad, 0, n);
    // Z = L(Y) [+u1]; Y = L(Z); Rb = L(Y) + u2*c1^T + u1*c2^T + b3 [u2 inline]
    agg128_k<0><<<gagg, blk, 0, stream>>>(Y, rowptr, eidx, ecoef, dinv, Z, u1, nullptr, nullptr, nullptr, n);
    agg128_k<1><<<gagg, blk, 0, stream>>>(Z, rowptr, eidx, ecoef, dinv, Y, nullptr, nullptr, nullptr, nullptr, n);
    agg128_k<2><<<gagg, blk, 0, stream>>>(Y, rowptr, eidx, ecoef, dinv, Rb, u1, c1, c2, b3, n);
    // fc1 (+relu): Rb -> Q
    gemm_mfma<false, false, true, true><<<gx, blk, 0, stream>>>(Rb, Bfc1, fc1_b, Q, 128, N3, N3, Mpad, 0, Mpad);
    // preds: Q @ Wc^T + bc -> out (f32, nontemporal)
    gemm_mfma<false, true, true, false><<<gx * 8, blk, 0, stream>>>(Q, Wc, bc, out, 128, NC, NC, n, 3, Mpad);
}

// Round 14
// 350.945 us; speedup vs baseline: 1.2316x; 1.2316x over previous
//
#include <hip/hip_runtime.h>

typedef unsigned short u16;
typedef __bf16 bf16x8 __attribute__((ext_vector_type(8)));
typedef float f32x4 __attribute__((ext_vector_type(4)));

__device__ __forceinline__ u16 f2bf(float f) {
    unsigned int u = __float_as_uint(f);
    unsigned int r = (u + 0x7FFFu + ((u >> 16) & 1u)) >> 16;
    return (u16)r;
}
__device__ __forceinline__ float bf_lo(unsigned int u) { return __uint_as_float(u << 16); }
__device__ __forceinline__ float bf_hi(unsigned int u) { return __uint_as_float(u & 0xFFFF0000u); }

#define GLOAD_LDS(gp, lp) \
    __builtin_amdgcn_global_load_lds( \
        (const __attribute__((address_space(1))) unsigned int*)(gp), \
        (__attribute__((address_space(3))) unsigned int*)(lp), 16, 0, 0)

// ---------------- graph preprocessing ----------------

__global__ void hist_k(const int* __restrict__ dst, int* __restrict__ deg, int nE) {
    int e = blockIdx.x * 256 + threadIdx.x;
    if (e < nE) atomicAdd(&deg[dst[e]], 1);
}

__global__ void scan_block_k(const int* __restrict__ deg, int* __restrict__ scanned,
                             int* __restrict__ bsums, int n) {
    __shared__ int s[1024];
    int i = blockIdx.x * 1024 + threadIdx.x;
    int v = (i < n) ? deg[i] : 0;
    s[threadIdx.x] = v;
    __syncthreads();
    for (int off = 1; off < 1024; off <<= 1) {
        int t = (threadIdx.x >= off) ? s[threadIdx.x - off] : 0;
        __syncthreads();
        s[threadIdx.x] += t;
        __syncthreads();
    }
    if (i < n) scanned[i] = s[threadIdx.x];
    if (threadIdx.x == 1023) bsums[blockIdx.x] = s[1023];
}

// inline bsums prefix (nb<=49), + dinv + wptr
__global__ void scan_final_dinv_k(const int* __restrict__ scanned, const int* __restrict__ deg,
                                  const int* __restrict__ bsums, int* __restrict__ rowptr,
                                  int* __restrict__ wptr, float* __restrict__ dinv,
                                  int n, int nE) {
    int i = blockIdx.x * 256 + threadIdx.x;
    if (i < n) {
        int pre = 0;
        int nbi = i >> 10;
        for (int j = 0; j < nbi; ++j) pre += bsums[j];
        int rp = scanned[i] - deg[i] + pre;
        rowptr[i] = rp;
        wptr[i] = rp;
        dinv[i] = rsqrtf((float)deg[i] + 1.0f);
    }
    if (i == 0) rowptr[n] = nE;
}

__global__ void csr_fill_k(const int* __restrict__ src, const int* __restrict__ dst,
                           int* __restrict__ wptr, const float* __restrict__ dinv,
                           int* __restrict__ eidx, float* __restrict__ ecoef, int nE) {
    int e = blockIdx.x * 256 + threadIdx.x;
    if (e >= nE) return;
    int d = dst[e], s = src[e];
    int p = atomicAdd(&wptr[d], 1);
    eidx[p] = s;
    ecoef[p] = dinv[s] * dinv[d];
}

// ---------------- single prep kernel: Wp chain, cvec, fc1^T, fc2xlabel ----------------
// blocks 0..511: Wp row chain; 512: c1/c2; 513..576: Bfc1; 577..704: Wc/bc

__global__ __launch_bounds__(256) void prep_all_k(
    const float* __restrict__ W1, const float* __restrict__ W2, const float* __restrict__ W3,
    const float* __restrict__ b1, const float* __restrict__ b2,
    const float* __restrict__ fc1_w, const float* __restrict__ fc2_w,
    const float* __restrict__ fc2_b, const float* __restrict__ labelm,
    u16* __restrict__ Wp, float* __restrict__ c1, float* __restrict__ c2,
    u16* __restrict__ Bfc1, u16* __restrict__ Wc, float* __restrict__ bc) {
    __shared__ float lds[16706];   // 66,824B: fc2 role needs 128*129+128+2
    const int b = blockIdx.x, tid = threadIdx.x;
    if (b < 512) {
        float* row = lds;          // 256
        float* t1r = lds + 256;    // 192
        row[tid] = (tid < 256) ? W1[b * 256 + tid] : 0.f;
        __syncthreads();
        if (tid < 192) {
            float s = 0.f;
            for (int k = 0; k < 256; ++k) s = fmaf(row[k], W2[k * 192 + tid], s);
            t1r[tid] = s;
        }
        __syncthreads();
        if (tid < 128) {
            float s = 0.f;
            for (int m = 0; m < 192; ++m) s = fmaf(t1r[m], W3[m * 128 + tid], s);
            Wp[(size_t)tid * 512 + b] = f2bf(s);
        }
    } else if (b == 512) {
        float* t1b = lds;
        if (tid < 192) {
            float s = 0.f;
            for (int k = 0; k < 256; ++k) s = fmaf(b1[k], W2[k * 192 + tid], s);
            t1b[tid] = s;
        }
        __syncthreads();
        if (tid < 128) {
            float a = 0.f, bb = 0.f;
            for (int m = 0; m < 192; ++m) {
                a  = fmaf(t1b[m], W3[m * 128 + tid], a);
                bb = fmaf(b2[m],  W3[m * 128 + tid], bb);
            }
            c1[tid] = a; c2[tid] = bb;
        }
    } else if (b < 577) {
        int idx = (b - 513) * 256 + tid;
        if (idx < 128 * 128) {
            int nn = idx >> 7, k = idx & 127;
            Bfc1[idx] = f2bf(fc1_w[k * 128 + nn]);
        }
    } else {
        const int cb = b - 577;    // 0..127
        float* w  = lds;            // 128*129
        float* lm = lds + 16512;    // 128
        float* red = lds + 16640;   // 2
        for (int t = tid; t < 128 * 128; t += 256)
            w[(t >> 7) * 129 + (t & 127)] = fc2_w[t];
        __syncthreads();
        for (int cc = 0; cc < 8; ++cc) {
            int c = cb * 8 + cc;
            if (tid < 128) lm[tid] = (c < 1000) ? labelm[(size_t)c * 128 + tid] : 0.f;
            __syncthreads();
            if (tid < 128) {
                float sum = 0.f;
                const float* wr = &w[tid * 129];
                for (int j = 0; j < 128; ++j) sum = fmaf(wr[j], lm[j], sum);
                Wc[(size_t)c * 128 + tid] = f2bf(sum);
                float p = fc2_b[tid] * lm[tid];
                for (int off = 32; off > 0; off >>= 1) p += __shfl_down(p, off);
                if ((tid & 63) == 0) red[tid >> 6] = p;
            }
            __syncthreads();
            if (tid == 0) bc[c] = red[0] + red[1];
            __syncthreads();
        }
    }
}

// ---------------- bf16 MFMA GEMM (BM=BN=128, BK=64, 4 waves, XCD swizzle) ----------------
// OUTF32 path: LDS-staged float4 epilogue (16B/lane stores)

template <bool CASTA, bool OUTF32, bool BIAS, bool RELU>
__global__ __launch_bounds__(256) void gemm_mfma(
    const void* __restrict__ Ap, const u16* __restrict__ Bt,
    const float* __restrict__ bias, void* __restrict__ Cout,
    int K, int Nout, int ldc, int Mout, int lgny, int Arows) {
    __shared__ __align__(16) u16 As[128 * 64];
    __shared__ __align__(16) u16 Bs[128 * 64];
    const int tid  = threadIdx.x;
    const int lane = tid & 63;
    const int w    = tid >> 6;
    const int wm   = w >> 1, wn = w & 1;

    const int nwg = gridDim.x, orig = blockIdx.x;
    const int q = nwg >> 3, r = nwg & 7;
    const int xcd = orig & 7, off = orig >> 3;
    const int tile = (xcd < r ? xcd * (q + 1) : r * (q + 1) + (xcd - r) * q) + off;
    const int ny = 1 << lgny;
    const int tx = tile >> lgny, ty = tile & (ny - 1);
    const size_t bm = (size_t)tx * 128;
    const size_t bn = (size_t)ty * 128;

    const int l7 = lane & 7;
    const int l3 = lane >> 3;
    const int kcs = l7 ^ l3;

    f32x4 acc[4][4] = {};

    for (int k0 = 0; k0 < K; k0 += 64) {
        if constexpr (CASTA) {
            const float* Af = (const float*)Ap;
            const int row = tid >> 1;
            const int half = tid & 1;
            const size_t grow = bm + row;
            const bool valid = grow < (size_t)Arows;
            const float4* g4 = (const float4*)(Af + grow * K + k0 + half * 32);
            float4 f[8];
#pragma unroll
            for (int j = 0; j < 8; ++j)
                f[j] = valid ? g4[j] : make_float4(0.f, 0.f, 0.f, 0.f);
#pragma unroll
            for (int j = 0; j < 4; ++j) {
                int kc = (half * 4 + j) ^ (row & 7);
                uint4 o;
                o.x = (unsigned)f2bf(f[2 * j].x)     | ((unsigned)f2bf(f[2 * j].y) << 16);
                o.y = (unsigned)f2bf(f[2 * j].z)     | ((unsigned)f2bf(f[2 * j].w) << 16);
                o.z = (unsigned)f2bf(f[2 * j + 1].x) | ((unsigned)f2bf(f[2 * j + 1].y) << 16);
                o.w = (unsigned)f2bf(f[2 * j + 1].z) | ((unsigned)f2bf(f[2 * j + 1].w) << 16);
                *(uint4*)((char*)As + row * 128 + kc * 16) = o;
            }
#pragma unroll
            for (int it = 0; it < 4; ++it) {
                const int r0 = w * 32 + it * 8;
                const u16* gB = Bt + ((size_t)(bn + r0 + l3) * K + k0) + kcs * 8;
                GLOAD_LDS(gB, Bs + r0 * 64);
            }
        } else {
            const u16* A = (const u16*)Ap;
#pragma unroll
            for (int it = 0; it < 4; ++it) {
                const int r0 = w * 32 + it * 8;
                const u16* gA = A + ((size_t)(bm + r0 + l3) * K + k0) + kcs * 8;
                GLOAD_LDS(gA, As + r0 * 64);
                const u16* gB = Bt + ((size_t)(bn + r0 + l3) * K + k0) + kcs * 8;
                GLOAD_LDS(gB, Bs + r0 * 64);
            }
        }
        __syncthreads();

#pragma unroll
        for (int ks = 0; ks < 2; ++ks) {
            bf16x8 av[4], bv[4];
#pragma unroll
            for (int i = 0; i < 4; ++i) {
                int row = wm * 64 + i * 16 + (lane & 15);
                int kc = (ks * 4 + (lane >> 4)) ^ (lane & 7);
                av[i] = *(const bf16x8*)((const char*)As + row * 128 + kc * 16);
            }
#pragma unroll
            for (int j = 0; j < 4; ++j) {
                int nn = wn * 64 + j * 16 + (lane & 15);
                int kc = (ks * 4 + (lane >> 4)) ^ (lane & 7);
                bv[j] = *(const bf16x8*)((const char*)Bs + nn * 128 + kc * 16);
            }
#pragma unroll
            for (int i = 0; i < 4; ++i)
#pragma unroll
                for (int j = 0; j < 4; ++j)
                    acc[i][j] = __builtin_amdgcn_mfma_f32_16x16x32_bf16(av[i], bv[j], acc[i][j], 0, 0, 0);
        }
        __syncthreads();
    }

    const int ccol  = lane & 15;
    const int crow4 = (lane >> 4) * 4;

    if constexpr (OUTF32) {
        // staged float4 epilogue: two 64-row halves through 32KB LDS scratch
        float* sc = (float*)As;   // 64 x 128 f32 = 32KB (reuses As+Bs)
        for (int rh = 0; rh < 2; ++rh) {
            __syncthreads();
            if (wm == rh) {
#pragma unroll
                for (int i = 0; i < 4; ++i)
#pragma unroll
                    for (int j = 0; j < 4; ++j)
#pragma unroll
                        for (int r2 = 0; r2 < 4; ++r2) {
                            int lr = i * 16 + crow4 + r2;        // 0..63
                            int lc = wn * 64 + j * 16 + ccol;    // 0..127
                            float v = acc[i][j][r2];
                            if constexpr (BIAS) v += bias[bn + lc];
                            if constexpr (RELU) v = fmaxf(v, 0.f);
                            sc[lr * 128 + lc] = v;
                        }
            }
            __syncthreads();
#pragma unroll
            for (int t = tid; t < 64 * 32; t += 256) {
                int lr = t >> 5;
                int f4 = t & 31;
                size_t gr = bm + rh * 64 + lr;
                size_t gc = bn + f4 * 4;
                if (gr < (size_t)Mout && gc + 3 < (size_t)Nout) {
                    float4 v = *(float4*)&sc[lr * 128 + f4 * 4];
                    *(float4*)&((float*)Cout)[gr * ldc + gc] = v;
                }
            }
        }
    } else {
#pragma unroll
        for (int i = 0; i < 4; ++i) {
#pragma unroll
            for (int j = 0; j < 4; ++j) {
#pragma unroll
                for (int r2 = 0; r2 < 4; ++r2) {
                    size_t gr = bm + wm * 64 + i * 16 + crow4 + r2;
                    size_t gc = bn + wn * 64 + j * 16 + ccol;
                    if (gr < (size_t)Mout && gc < (size_t)Nout) {
                        float v = acc[i][j][r2];
                        if constexpr (BIAS) v += bias[gc];
                        if constexpr (RELU) v = fmaxf(v, 0.f);
                        ((u16*)Cout)[gr * ldc + gc] = f2bf(v);
                    }
                }
            }
        }
    }
}

// ---------------- aggregation: 16-lane subgroups, 16 nodes/block, 8x unroll ----------------
// MODE 0: also write u1[node]; MODE 1: plain; MODE 2: inline u2 + rank-1 corrections

template <int MODE>
__global__ __launch_bounds__(256) void agg128_k(
    const u16* __restrict__ xw, const int* __restrict__ rowptr,
    const int* __restrict__ eidx, const float* __restrict__ ecoef,
    const float* __restrict__ dinv, u16* __restrict__ out,
    float* __restrict__ u1, const float* __restrict__ c1,
    const float* __restrict__ c2, const float* __restrict__ b3, int n) {
    const int tid = threadIdx.x;
    const int sub = tid >> 4;
    const int fl  = tid & 15;
    int node = blockIdx.x * 16 + sub;
    if (node >= n) return;

    const uint4* xv = (const uint4*)xw;
    float di = dinv[node];
    float s = di * di;
    uint4 a = xv[(size_t)node * 16 + fl];
    float acc[8];
    acc[0] = s * bf_lo(a.x); acc[1] = s * bf_hi(a.x);
    acc[2] = s * bf_lo(a.y); acc[3] = s * bf_hi(a.y);
    acc[4] = s * bf_lo(a.z); acc[5] = s * bf_hi(a.z);
    acc[6] = s * bf_lo(a.w); acc[7] = s * bf_hi(a.w);
    float usum = 0.f;

    const int beg = rowptr[node], end = rowptr[node + 1];
    int e = beg;
    for (; e + 7 < end; e += 8) {
        int sn[8]; float cf[8]; uint4 v[8];
#pragma unroll
        for (int q = 0; q < 8; ++q) { sn[q] = eidx[e + q]; cf[q] = ecoef[e + q]; }
#pragma unroll
        for (int q = 0; q < 8; ++q) v[q] = xv[(size_t)sn[q] * 16 + fl];
#pragma unroll
        for (int q = 0; q < 8; ++q) {
            if constexpr (MODE == 0) usum += cf[q];
            if constexpr (MODE == 2) usum = fmaf(cf[q], u1[sn[q]], usum);
            acc[0] = fmaf(cf[q], bf_lo(v[q].x), acc[0]); acc[1] = fmaf(cf[q], bf_hi(v[q].x), acc[1]);
            acc[2] = fmaf(cf[q], bf_lo(v[q].y), acc[2]); acc[3] = fmaf(cf[q], bf_hi(v[q].y), acc[3]);
            acc[4] = fmaf(cf[q], bf_lo(v[q].z), acc[4]); acc[5] = fmaf(cf[q], bf_hi(v[q].z), acc[5]);
            acc[6] = fmaf(cf[q], bf_lo(v[q].w), acc[6]); acc[7] = fmaf(cf[q], bf_hi(v[q].w), acc[7]);
        }
    }
    for (; e < end; ++e) {
        int sn = eidx[e];
        float c = ecoef[e];
        uint4 v = xv[(size_t)sn * 16 + fl];
        if constexpr (MODE == 0) usum += c;
        if constexpr (MODE == 2) usum = fmaf(c, u1[sn], usum);
        acc[0] = fmaf(c, bf_lo(v.x), acc[0]); acc[1] = fmaf(c, bf_hi(v.x), acc[1]);
        acc[2] = fmaf(c, bf_lo(v.y), acc[2]); acc[3] = fmaf(c, bf_hi(v.y), acc[3]);
        acc[4] = fmaf(c, bf_lo(v.z), acc[4]); acc[5] = fmaf(c, bf_hi(v.z), acc[5]);
        acc[6] = fmaf(c, bf_lo(v.w), acc[6]); acc[7] = fmaf(c, bf_hi(v.w), acc[7]);
    }

    if constexpr (MODE == 0) {
        if (fl == 0) u1[node] = s + usum;
    }
    if constexpr (MODE == 2) {
        float u1n = u1[node];
        float u2n = s * u1n + usum;
        float4 c1a = ((const float4*)c1)[fl * 2], c1b = ((const float4*)c1)[fl * 2 + 1];
        float4 c2a = ((const float4*)c2)[fl * 2], c2b = ((const float4*)c2)[fl * 2 + 1];
        float4 b3a = ((const float4*)b3)[fl * 2], b3b = ((const float4*)b3)[fl * 2 + 1];
        acc[0] += u2n * c1a.x + u1n * c2a.x + b3a.x;
        acc[1] += u2n * c1a.y + u1n * c2a.y + b3a.y;
        acc[2] += u2n * c1a.z + u1n * c2a.z + b3a.z;
        acc[3] += u2n * c1a.w + u1n * c2a.w + b3a.w;
        acc[4] += u2n * c1b.x + u1n * c2b.x + b3b.x;
        acc[5] += u2n * c1b.y + u1n * c2b.y + b3b.y;
        acc[6] += u2n * c1b.z + u1n * c2b.z + b3b.z;
        acc[7] += u2n * c1b.w + u1n * c2b.w + b3b.w;
    }

    uint4 o;
    o.x = (unsigned)f2bf(acc[0]) | ((unsigned)f2bf(acc[1]) << 16);
    o.y = (unsigned)f2bf(acc[2]) | ((unsigned)f2bf(acc[3]) << 16);
    o.z = (unsigned)f2bf(acc[4]) | ((unsigned)f2bf(acc[5]) << 16);
    o.w = (unsigned)f2bf(acc[6]) | ((unsigned)f2bf(acc[7]) << 16);
    ((uint4*)out)[(size_t)node * 16 + fl] = o;
}

// ---------------- launcher ----------------

extern "C" void kernel_launch(void* const* d_in, const int* in_sizes, int n_in,
                              void* d_out, int out_size, void* d_ws, size_t ws_size,
                              hipStream_t stream) {
    const float* nodes  = (const float*)d_in[0];
    const int*   edges  = (const int*)d_in[1];
    const float* labelm = (const float*)d_in[2];
    const float* W1 = (const float*)d_in[3];
    const float* b1 = (const float*)d_in[4];
    const float* W2 = (const float*)d_in[5];
    const float* b2 = (const float*)d_in[6];
    const float* W3 = (const float*)d_in[7];
    const float* b3 = (const float*)d_in[8];
    const float* fc1_w = (const float*)d_in[9];
    const float* fc1_b = (const float*)d_in[10];
    const float* fc2_w = (const float*)d_in[11];
    const float* fc2_b = (const float*)d_in[12];
    float* out = (float*)d_out;

    const int DIM = 512, N3 = 128, NC = 1000;
    const int n  = in_sizes[0] / DIM;   // 50000
    const int nE = in_sizes[1] / 2;     // 800000
    const int Mpad = 50048;             // 391 * 128
    const int* src = edges;
    const int* dst = edges + nE;

    // d_out scratch: Y, Z (dead before preds writes)
    u16* Y = (u16*)((char*)d_out + 67108864);      // 12.8MB
    u16* Z = (u16*)((char*)d_out + 100663296);     // 12.8MB

    // ws layout (bytes)
    char* ws = (char*)d_ws;
    u16*   Q      = (u16*)(ws);                  // 12,812,288
    u16*   Rb     = (u16*)(ws + 12812288);       // 12,812,288
    u16*   Wp     = (u16*)(ws + 26017792);       // 131,072
    u16*   Bfc1   = (u16*)(ws + 26148864);       // 32,768
    u16*   Wc     = (u16*)(ws + 26181632);       // 262,144
    float* bc     = (float*)(ws + 26443776);     // 4,096
    float* c1     = (float*)(ws + 26447872);     // 512
    float* c2     = (float*)(ws + 26448384);     // 512
    float* u1     = (float*)(ws + 26448896);     // 200,000
    int*   deg_i  = (int*)(ws + 26848896);       // 200,000
    float* dinv   = (float*)(ws + 27048896);     // 200,000
    int*   rowptr = (int*)(ws + 27248896);       // 200,064
    int*   wptr   = (int*)(ws + 27448960);       // 200,000
    int*   scanned= (int*)(ws + 27648960);       // 200,000
    int*   bsums  = (int*)(ws + 27848960);       // 256
    int*   eidx   = (int*)(ws + 27849216);       // 3,200,000
    float* ecoef  = (float*)(ws + 31049216);     // 3,200,000 (end ~34.2MB)

    // graph preprocessing (5 dispatches incl. memset)
    hipMemsetAsync(deg_i, 0, (size_t)n * 4, stream);
    hist_k<<<(nE + 255) / 256, 256, 0, stream>>>(dst, deg_i, nE);
    int nb = (n + 1023) / 1024;
    scan_block_k<<<nb, 1024, 0, stream>>>(deg_i, scanned, bsums, n);
    scan_final_dinv_k<<<(n + 255) / 256, 256, 0, stream>>>(scanned, deg_i, bsums, rowptr, wptr, dinv, n, nE);
    csr_fill_k<<<(nE + 255) / 256, 256, 0, stream>>>(src, dst, wptr, dinv, eidx, ecoef, nE);

    // all weight prep in one kernel
    prep_all_k<<<705, 256, 0, stream>>>(W1, W2, W3, b1, b2, fc1_w, fc2_w, fc2_b, labelm,
                                        Wp, c1, c2, Bfc1, Wc, bc);

    const int gx = Mpad / 128;  // 391
    dim3 blk(256);
    const int gagg = (n + 15) / 16;   // 3125 blocks

    // Y = cast(nodes) @ Wp^T
    gemm_mfma<true, false, false, false><<<gx, blk, 0, stream>>>(nodes, Wp, nullptr, Y, 512, N3, N3, Mpad, 0, n);
    // Z = L(Y) [+u1]; Y = L(Z); Rb = L(Y) + u2*c1^T + u1*c2^T + b3 [u2 inline]
    agg128_k<0><<<gagg, blk, 0, stream>>>(Y, rowptr, eidx, ecoef, dinv, Z, u1, nullptr, nullptr, nullptr, n);
    agg128_k<1><<<gagg, blk, 0, stream>>>(Z, rowptr, eidx, ecoef, dinv, Y, nullptr, nullptr, nullptr, nullptr, n);
    agg128_k<2><<<gagg, blk, 0, stream>>>(Y, rowptr, eidx, ecoef, dinv, Rb, u1, c1, c2, b3, n);
    // fc1 (+relu): Rb -> Q
    gemm_mfma<false, false, true, true><<<gx, blk, 0, stream>>>(Rb, Bfc1, fc1_b, Q, 128, N3, N3, Mpad, 0, Mpad);
    // preds: Q @ Wc^T + bc -> out (f32, staged float4 epilogue)
    gemm_mfma<false, true, true, false><<<gx * 8, blk, 0, stream>>>(Q, Wc, bc, out, 128, NC, NC, n, 3, Mpad);
}